// Round 20
// baseline (174.595 us; speedup 1.0000x reference)
//
#include <hip/hip_runtime.h>
#include <hip/hip_bf16.h>

#define S 4096
#define DM 512
#define HH 8
#define DK 64
#define MT 8192     // B*S

typedef __attribute__((ext_vector_type(8)))  short bf16x8;
typedef __attribute__((ext_vector_type(4)))  float f32x4;
typedef __attribute__((ext_vector_type(16))) float f32x16;
typedef __attribute__((ext_vector_type(4)))  unsigned int u32x4;

#define CQ 0.18033688011112042f   // 0.125 * log2(e), folded into Q projection

__device__ __forceinline__ short f2bs(float x) {
    __hip_bfloat16 h = __float2bfloat16(x);
    return *reinterpret_cast<short*>(&h);
}

__device__ __forceinline__ bf16x8 pack8(const float4& a, const float4& b) {
    bf16x8 r;
    r[0] = f2bs(a.x); r[1] = f2bs(a.y); r[2] = f2bs(a.z); r[3] = f2bs(a.w);
    r[4] = f2bs(b.x); r[5] = f2bs(b.y); r[6] = f2bs(b.z); r[7] = f2bs(b.w);
    return r;
}

__device__ __forceinline__ unsigned cvtpk(float lo, float hi) {
    unsigned r;
    asm("v_cvt_pk_bf16_f32 %0, %1, %2" : "=v"(r) : "v"(lo), "v"(hi));
    return r;
}

__device__ __forceinline__ bf16x8 mk_pb(unsigned a, unsigned b, unsigned c, unsigned d) {
    u32x4 t; t[0] = a; t[1] = b; t[2] = c; t[3] = d;
    return __builtin_bit_cast(bf16x8, t);
}

__device__ __forceinline__ void gld_lds16(const void* gp, void* lp) {
    __builtin_amdgcn_global_load_lds(
        (const __attribute__((address_space(1))) void*)gp,
        (__attribute__((address_space(3))) void*)lp, 16, 0, 0);
}
__device__ __forceinline__ void gld_lds4(const void* gp, void* lp) {
    __builtin_amdgcn_global_load_lds(
        (const __attribute__((address_space(1))) void*)gp,
        (__attribute__((address_space(3))) void*)lp, 4, 0, 0);
}

// ---------------- Fused QKV projection (frag-major K/V outputs) ------------
// Flat grid 1536, XCD-swizzled. Blocks 0..31 also convert mask -> f32 bias.
// Q: bf16 [bh][s][64] scaled by CQ.
// K frag-major: KF[(((bh*128 + s/32)*4 + d/16)*512) + ((s&31)+32*((d>>3)&1))*8 + (d&7)]
// V frag-major: VF[(((bh*256 + s/16)*2 + d/32)*512) + ((d&31)+32*((s>>3)&1))*8 + (s&7)]
// => each 64-key step's K frags (8KB) and V frags (8KB) are CONTIGUOUS.
__global__ __launch_bounds__(256, 4)
void qkv_gemm(const float* __restrict__ Xq, const float* __restrict__ Xk,
              const float* __restrict__ Xv,
              const float* __restrict__ Wq, const float* __restrict__ Wk,
              const float* __restrict__ Wv,
              const float* __restrict__ Bq, const float* __restrict__ Bk,
              const float* __restrict__ Bv,
              const int* __restrict__ mask, float* __restrict__ maskf,
              unsigned short* __restrict__ Yq, unsigned short* __restrict__ Yk,
              unsigned short* __restrict__ Yv)
{
    __shared__ char As[128 * 128];
    __shared__ char Bs[64 * 128];
    const int bid  = blockIdx.x;
    const int t = threadIdx.x;
    if (bid < 32) {
        int i = bid * 256 + t;            // 32*256 = 8192 = B*S
        maskf[i] = mask[i] ? 0.f : -3e38f;
    }
    const int work = (bid & 7) * 192 + (bid >> 3);
    const int gp   = work >> 3;
    const int mat  = gp >> 6;
    const int m0   = (gp & 63) * 128;
    const int n0   = (work & 7) * 64;
    const float* X    = mat == 0 ? Xq : (mat == 1 ? Xk : Xv);
    const float* W    = mat == 0 ? Wq : (mat == 1 ? Wk : Wv);
    const float* bias = mat == 0 ? Bq : (mat == 1 ? Bk : Bv);

    const int l = t & 63, w = t >> 6;
    const int wr = w >> 1, wc = w & 1;
    const int lr = l & 15, lg = l >> 4;
    const int srow = t >> 3, schk = t & 7;
    const int sswz = (schk ^ (srow & 7)) * 16;

    float4 fA[4][2]; float4 fB[2][2];
    auto loadA = [&](int k0) {
        #pragma unroll
        for (int i = 0; i < 4; ++i) {
            const float* p = X + (size_t)(m0 + srow + 32 * i) * DM + k0 + schk * 8;
            fA[i][0] = *(const float4*)p;
            fA[i][1] = *(const float4*)(p + 4);
        }
    };
    auto loadB = [&](int k0) {
        #pragma unroll
        for (int i = 0; i < 2; ++i) {
            const float* p = W + (size_t)(n0 + srow + 32 * i) * DM + k0 + schk * 8;
            fB[i][0] = *(const float4*)p;
            fB[i][1] = *(const float4*)(p + 4);
        }
    };

    loadA(0); loadB(0);

    f32x4 acc[4][2];
    #pragma unroll
    for (int fm = 0; fm < 4; ++fm)
        #pragma unroll
        for (int fn = 0; fn < 2; ++fn) acc[fm][fn] = f32x4{0.f, 0.f, 0.f, 0.f};

    #pragma unroll
    for (int kt = 0; kt < 8; ++kt) {
        bf16x8 wA[4], wB[2];
        #pragma unroll
        for (int i = 0; i < 4; ++i) wA[i] = pack8(fA[i][0], fA[i][1]);
        #pragma unroll
        for (int i = 0; i < 2; ++i) wB[i] = pack8(fB[i][0], fB[i][1]);

        if (kt < 7) { loadA((kt + 1) * 64); loadB((kt + 1) * 64); }

        __syncthreads();
        #pragma unroll
        for (int i = 0; i < 4; ++i)
            *(bf16x8*)(As + (srow + 32 * i) * 128 + sswz) = wA[i];
        #pragma unroll
        for (int i = 0; i < 2; ++i)
            *(bf16x8*)(Bs + (srow + 32 * i) * 128 + sswz) = wB[i];
        __syncthreads();

        #pragma unroll
        for (int kc = 0; kc < 2; ++kc) {
            bf16x8 af[4], bfr[2];
            #pragma unroll
            for (int fm = 0; fm < 4; ++fm) {
                int row = wr * 64 + fm * 16 + lr;
                af[fm] = *(const bf16x8*)(As + row * 128 + (((kc * 4 + lg) ^ (row & 7)) * 16));
            }
            #pragma unroll
            for (int fn = 0; fn < 2; ++fn) {
                int row = wc * 32 + fn * 16 + lr;
                bfr[fn] = *(const bf16x8*)(Bs + row * 128 + (((kc * 4 + lg) ^ (row & 7)) * 16));
            }
            #pragma unroll
            for (int fm = 0; fm < 4; ++fm)
                #pragma unroll
                for (int fn = 0; fn < 2; ++fn)
                    acc[fm][fn] = __builtin_amdgcn_mfma_f32_16x16x32_bf16(af[fm], bfr[fn], acc[fm][fn], 0, 0, 0);
        }
    }

    #pragma unroll
    for (int fm = 0; fm < 4; ++fm) {
        #pragma unroll
        for (int fn = 0; fn < 2; ++fn) {
            int n = n0 + wc * 32 + fn * 16 + lr;
            float bn = bias[n];
            int mbase = m0 + wr * 64 + fm * 16 + lg * 4;
            int h = n >> 6, d = n & 63;
            int bb = mbase >> 12, s0 = mbase & (S - 1);
            if (mat == 0) {
                #pragma unroll
                for (int r = 0; r < 4; ++r)
                    Yq[(((size_t)(bb * HH + h)) * S + s0 + r) * DK + d] =
                        (unsigned short)f2bs((acc[fm][fn][r] + bn) * CQ);
            } else if (mat == 1) {
                int c   = (d >> 4) & 3;
                int hi2 = (d >> 3) & 1;
                int ii  = d & 7;
                size_t blkb = ((((size_t)(bb * HH + h)) * 128 + (s0 >> 5)) * 4 + c) * 512;
                int lanebase = (s0 & 31) + 32 * hi2;
                #pragma unroll
                for (int r = 0; r < 4; ++r)
                    Yk[blkb + (size_t)(lanebase + r) * 8 + ii] =
                        (unsigned short)f2bs(acc[fm][fn][r] + bn);
            } else {
                int dt2  = (d >> 5) & 1;
                int hi_s = (s0 >> 3) & 1;
                int lane = (d & 31) + 32 * hi_s;
                size_t base = ((((size_t)(bb * HH + h)) * 256 + (s0 >> 4)) * 2 + dt2) * 512
                            + (size_t)lane * 8 + (s0 & 7);
                ushort4 u;
                u.x = (unsigned short)f2bs(acc[fm][fn][0] + bn);
                u.y = (unsigned short)f2bs(acc[fm][fn][1] + bn);
                u.z = (unsigned short)f2bs(acc[fm][fn][2] + bn);
                u.w = (unsigned short)f2bs(acc[fm][fn][3] + bn);
                *(ushort4*)(Yv + base) = u;
            }
        }
    }
}

// ---------------- Output projection (XCD-swizzled) -------------------------
__global__ __launch_bounds__(256, 2)
void out_gemm(const short* __restrict__ Xb, const float* __restrict__ W,
              const float* __restrict__ bias, float* __restrict__ Y)
{
    __shared__ char As[128 * 128];
    __shared__ char Bs[64 * 128];
    const int bid  = blockIdx.x;
    const int work = (bid & 7) * 64 + (bid >> 3);
    const int n0 = (work & 7) * 64;
    const int m0 = (work >> 3) * 128;

    const int t = threadIdx.x, l = t & 63, w = t >> 6;
    const int wr = w >> 1, wc = w & 1;
    const int lr = l & 15, lg = l >> 4;
    const int srow = t >> 3, schk = t & 7;
    const int sswz = (schk ^ (srow & 7)) * 16;

    float4 fB[2][2]; bf16x8 rA[4];
    auto loadA = [&](int k0) {
        #pragma unroll
        for (int i = 0; i < 4; ++i)
            rA[i] = *(const bf16x8*)(Xb + (size_t)(m0 + srow + 32 * i) * DM + k0 + schk * 8);
    };
    auto loadB = [&](int k0) {
        #pragma unroll
        for (int i = 0; i < 2; ++i) {
            const float* p = W + (size_t)(n0 + srow + 32 * i) * DM + k0 + schk * 8;
            fB[i][0] = *(const float4*)p;
            fB[i][1] = *(const float4*)(p + 4);
        }
    };

    loadA(0); loadB(0);

    f32x4 acc[4][2];
    #pragma unroll
    for (int fm = 0; fm < 4; ++fm)
        #pragma unroll
        for (int fn = 0; fn < 2; ++fn) acc[fm][fn] = f32x4{0.f, 0.f, 0.f, 0.f};

    #pragma unroll
    for (int kt = 0; kt < 8; ++kt) {
        bf16x8 wA[4], wB[2];
        #pragma unroll
        for (int i = 0; i < 4; ++i) wA[i] = rA[i];
        #pragma unroll
        for (int i = 0; i < 2; ++i) wB[i] = pack8(fB[i][0], fB[i][1]);

        if (kt < 7) { loadA((kt + 1) * 64); loadB((kt + 1) * 64); }

        __syncthreads();
        #pragma unroll
        for (int i = 0; i < 4; ++i)
            *(bf16x8*)(As + (srow + 32 * i) * 128 + sswz) = wA[i];
        #pragma unroll
        for (int i = 0; i < 2; ++i)
            *(bf16x8*)(Bs + (srow + 32 * i) * 128 + sswz) = wB[i];
        __syncthreads();

        #pragma unroll
        for (int kc = 0; kc < 2; ++kc) {
            bf16x8 af[4], bfr[2];
            #pragma unroll
            for (int fm = 0; fm < 4; ++fm) {
                int row = wr * 64 + fm * 16 + lr;
                af[fm] = *(const bf16x8*)(As + row * 128 + (((kc * 4 + lg) ^ (row & 7)) * 16));
            }
            #pragma unroll
            for (int fn = 0; fn < 2; ++fn) {
                int row = wc * 32 + fn * 16 + lr;
                bfr[fn] = *(const bf16x8*)(Bs + row * 128 + (((kc * 4 + lg) ^ (row & 7)) * 16));
            }
            #pragma unroll
            for (int fm = 0; fm < 4; ++fm)
                #pragma unroll
                for (int fn = 0; fn < 2; ++fn)
                    acc[fm][fn] = __builtin_amdgcn_mfma_f32_16x16x32_bf16(af[fm], bfr[fn], acc[fm][fn], 0, 0, 0);
        }
    }

    #pragma unroll
    for (int fm = 0; fm < 4; ++fm) {
        #pragma unroll
        for (int fn = 0; fn < 2; ++fn) {
            int n = n0 + wc * 32 + fn * 16 + lr;
            float bn = bias[n];
            int mbase = m0 + wr * 64 + fm * 16 + lg * 4;
            #pragma unroll
            for (int r = 0; r < 4; ++r)
                Y[(size_t)(mbase + r) * DM + n] = acc[fm][fn][r] + bn;
        }
    }
}

// ---------------- Flash attention: wave-private staging, barrier-free ------
// Each wave stages its OWN kw-half (K 4KB + V 4KB + mask 256B = 9 gld_lds
// ops) into a PRIVATE double-buffered LDS region, paced by per-wave counted
// s_waitcnt vmcnt(9) (steady state: 18 outstanding, 2-step prefetch).
// ZERO in-loop barriers -> no cross-wave convoy. Frag layouts, math, and
// epilogue identical to R14. 66KB LDS -> 2 blocks/CU, 8 self-paced waves.
__global__ __launch_bounds__(256, 2)
void flash_mfma(const short* __restrict__ qh,
                const short* __restrict__ kfb,
                const short* __restrict__ vfb,
                const float* __restrict__ maskf,
                unsigned short* __restrict__ att)
{
    const int bid  = blockIdx.x;
    const int work = (bid & 7) * 128 + (bid >> 3);
    const int bh = work >> 6, b = bh >> 3, h = bh & 7;
    const int q0 = (work & 63) * 64;
    const int t = threadIdx.x, w = t >> 6, l = t & 63;
    const int l31 = l & 31, hi = l >> 5;
    const int kw = w & 1, qw = w >> 1;

    // per-wave region: 2 buffers x (K 4KB + V 4KB + mask 256B) = 16896 B
    __shared__ char sBuf[4 * 16896];
    char* wbase = sBuf + w * 16896;
    char* bufA  = wbase;
    char* bufB  = wbase + 8448;

    const short* qg = qh + ((size_t)bh * S + q0 + qw * 32 + l31) * DK;
    bf16x8 qf[4];
    #pragma unroll
    for (int c = 0; c < 4; ++c)
        qf[c] = *(const bf16x8*)(qg + c * 16 + hi * 8);

    f32x16 oc[2];
    #pragma unroll
    for (int dt = 0; dt < 2; ++dt)
        #pragma unroll
        for (int r = 0; r < 16; ++r) oc[dt][r] = 0.f;
    float ls = 0.f;

    // wave's global sources: its kw-half of each step's contiguous frags
    const char* kgW = (const char*)(kfb + (size_t)bh * 262144) + kw * 4096 + (size_t)l * 16;
    const char* vgW = (const char*)(vfb + (size_t)bh * 262144) + kw * 4096 + (size_t)l * 16;
    const char* mg0 = (const char*)(maskf + b * S) + (size_t)l * 4;

    // 9 vm-ops per stage: 4x K 1KB + 4x V 1KB + 1x mask 256B
    auto stageW = [&](char* dst, int step) {
        const char* kg = kgW + (size_t)step * 8192;
        const char* vg = vgW + (size_t)step * 8192;
        #pragma unroll
        for (int i = 0; i < 4; ++i) gld_lds16(kg + i * 1024, dst + i * 1024);
        #pragma unroll
        for (int i = 0; i < 4; ++i) gld_lds16(vg + i * 1024, dst + 4096 + i * 1024);
        gld_lds4(mg0 + (size_t)step * 256, dst + 8192);
    };

    auto computeW = [&](const char* buf) {
        // mask-bias C-init (broadcast b128 reads from this wave's copy)
        const char* mb = buf + 8192 + kw * 128 + hi * 16;
        f32x4 m40 = *(const f32x4*)(mb);
        f32x4 m41 = *(const f32x4*)(mb + 32);
        f32x4 m42 = *(const f32x4*)(mb + 64);
        f32x4 m43 = *(const f32x4*)(mb + 96);
        f32x16 sc;
        #pragma unroll
        for (int o = 0; o < 4; ++o) {
            sc[o] = m40[o]; sc[4 + o] = m41[o];
            sc[8 + o] = m42[o]; sc[12 + o] = m43[o];
        }
        // K frags (lane-contiguous b128)
        const char* kbase = buf + l * 16;
        bf16x8 kf0 = *(const bf16x8*)(kbase);
        bf16x8 kf1 = *(const bf16x8*)(kbase + 1024);
        bf16x8 kf2 = *(const bf16x8*)(kbase + 2048);
        bf16x8 kf3 = *(const bf16x8*)(kbase + 3072);
        __builtin_amdgcn_s_setprio(1);
        sc = __builtin_amdgcn_mfma_f32_32x32x16_bf16(kf0, qf[0], sc, 0, 0, 0);
        sc = __builtin_amdgcn_mfma_f32_32x32x16_bf16(kf1, qf[1], sc, 0, 0, 0);
        sc = __builtin_amdgcn_mfma_f32_32x32x16_bf16(kf2, qf[2], sc, 0, 0, 0);
        sc = __builtin_amdgcn_mfma_f32_32x32x16_bf16(kf3, qf[3], sc, 0, 0, 0);
        __builtin_amdgcn_s_setprio(0);

        // V frags (this wave's 32 keys)
        const char* vbase = buf + 4096 + l * 16;
        bf16x8 vf00 = *(const bf16x8*)(vbase);
        bf16x8 vf01 = *(const bf16x8*)(vbase + 1024);
        bf16x8 vf10 = *(const bf16x8*)(vbase + 2048);
        bf16x8 vf11 = *(const bf16x8*)(vbase + 3072);

        // p = exp2(s); per-lane l partial
        float p[16];
        #pragma unroll
        for (int r = 0; r < 16; ++r) p[r] = exp2f(sc[r]);
        float a0 = 0.f;
        #pragma unroll
        for (int r = 0; r < 16; r += 4)
            a0 += (p[r] + p[r + 1]) + (p[r + 2] + p[r + 3]);
        ls += a0;

        // cvt_pk + permlane32_swap -> PV B-frags
        unsigned A0 = cvtpk(p[0],  p[1]),  B0r = cvtpk(p[2],  p[3]);
        unsigned A1 = cvtpk(p[4],  p[5]),  B1r = cvtpk(p[6],  p[7]);
        unsigned A2 = cvtpk(p[8],  p[9]),  B2r = cvtpk(p[10], p[11]);
        unsigned A3 = cvtpk(p[12], p[13]), B3r = cvtpk(p[14], p[15]);
        asm("v_permlane32_swap_b32 %0, %1" : "+v"(A0), "+v"(A1));
        asm("v_permlane32_swap_b32 %0, %1" : "+v"(B0r), "+v"(B1r));
        asm("v_permlane32_swap_b32 %0, %1" : "+v"(A2), "+v"(A3));
        asm("v_permlane32_swap_b32 %0, %1" : "+v"(B2r), "+v"(B3r));
        bf16x8 pb0 = mk_pb(A0, B0r, A1, B1r);
        bf16x8 pb1 = mk_pb(A2, B2r, A3, B3r);

        // PV
        __builtin_amdgcn_s_setprio(1);
        oc[0] = __builtin_amdgcn_mfma_f32_32x32x16_bf16(vf00, pb0, oc[0], 0, 0, 0);
        oc[1] = __builtin_amdgcn_mfma_f32_32x32x16_bf16(vf01, pb0, oc[1], 0, 0, 0);
        oc[0] = __builtin_amdgcn_mfma_f32_32x32x16_bf16(vf10, pb1, oc[0], 0, 0, 0);
        oc[1] = __builtin_amdgcn_mfma_f32_32x32x16_bf16(vf11, pb1, oc[1], 0, 0, 0);
        __builtin_amdgcn_s_setprio(0);
    };

    // prologue: 2-step prefetch (18 vm-ops outstanding)
    stageW(bufA, 0);
    stageW(bufB, 1);

    // self-paced loop: wait own oldest 9 ops, compute, restage same buffer
    for (int it = 0; it < 32; ++it) {
        const int s0 = it * 2;
        asm volatile("s_waitcnt vmcnt(9)" ::: "memory");   // bufA (step s0) ready
        __builtin_amdgcn_sched_barrier(0);
        computeW(bufA);
        asm volatile("s_waitcnt lgkmcnt(0)" ::: "memory"); // our reads of bufA done
        __builtin_amdgcn_sched_barrier(0);
        if (s0 + 2 < 64) stageW(bufA, s0 + 2);

        if (it < 31) {
            asm volatile("s_waitcnt vmcnt(9)" ::: "memory");  // bufB (s0+1) ready
        } else {
            asm volatile("s_waitcnt vmcnt(0)" ::: "memory");  // final drain
        }
        __builtin_amdgcn_sched_barrier(0);
        computeW(bufB);
        asm volatile("s_waitcnt lgkmcnt(0)" ::: "memory");
        __builtin_amdgcn_sched_barrier(0);
        if (s0 + 3 < 64) stageW(bufB, s0 + 3);
    }

    // ---- cross-wave (kw) reduction, then normalize + write (reuse sBuf)
    __syncthreads();
    float* scr = (float*)sBuf;
    float* pp  = scr + (size_t)(qw * 64 + l) * 33;
    if (kw == 1) {
        #pragma unroll
        for (int r = 0; r < 16; ++r) { pp[r] = oc[0][r]; pp[16 + r] = oc[1][r]; }
        pp[32] = ls;
    }
    __syncthreads();
    if (kw == 0) {
        #pragma unroll
        for (int r = 0; r < 16; ++r) { oc[0][r] += pp[r]; oc[1][r] += pp[16 + r]; }
        ls += pp[32];
        ls += __shfl_xor(ls, 32);
        const float linv = 1.0f / ls;
        unsigned short* ap = att + ((size_t)(b * S + q0 + qw * 32 + l31)) * DM + h * DK;
        #pragma unroll
        for (int dt = 0; dt < 2; ++dt)
            #pragma unroll
            for (int g = 0; g < 4; ++g) {
                uint2 u;
                u.x = cvtpk(oc[dt][g * 4 + 0] * linv, oc[dt][g * 4 + 1] * linv);
                u.y = cvtpk(oc[dt][g * 4 + 2] * linv, oc[dt][g * 4 + 3] * linv);
                *(uint2*)(ap + dt * 32 + g * 8 + hi * 4) = u;
            }
    }
}

extern "C" void kernel_launch(void* const* d_in, const int* in_sizes, int n_in,
                              void* d_out, int out_size, void* d_ws, size_t ws_size,
                              hipStream_t stream) {
    const float* q    = (const float*)d_in[0];
    const float* k    = (const float*)d_in[1];
    const float* v    = (const float*)d_in[2];
    const int*   mask = (const int*)  d_in[3];
    const float* wq   = (const float*)d_in[4];
    const float* bq   = (const float*)d_in[5];
    const float* wk   = (const float*)d_in[6];
    const float* bk   = (const float*)d_in[7];
    const float* wv   = (const float*)d_in[8];
    const float* bv   = (const float*)d_in[9];
    const float* wo   = (const float*)d_in[10];
    const float* bo   = (const float*)d_in[11];
    float* out = (float*)d_out;

    char* wsb = (char*)d_ws;
    unsigned short* qh    = (unsigned short*)(wsb);
    unsigned short* kfb   = (unsigned short*)(wsb + (size_t)8  * 1024 * 1024);
    unsigned short* vfb   = (unsigned short*)(wsb + (size_t)16 * 1024 * 1024);
    unsigned short* att   = (unsigned short*)(wsb + (size_t)24 * 1024 * 1024);
    float*          maskf = (float*)         (wsb + (size_t)32 * 1024 * 1024);

    dim3 blk(256);
    qkv_gemm<<<dim3(1536), blk, 0, stream>>>(q, k, v, wq, wk, wv, bq, bk, bv,
                                     mask, maskf, qh, kfb, vfb);

    flash_mfma<<<dim3(1024), blk, 0, stream>>>((const short*)qh, (const short*)kfb,
                                     (const short*)vfb, maskf, att);

    out_gemm<<<dim3(512), blk, 0, stream>>>((const short*)att, wo, bo, out);
}

// Round 21
// 161.958 us; speedup vs baseline: 1.0780x; 1.0780x over previous
//
#include <hip/hip_runtime.h>
#include <hip/hip_bf16.h>

#define S 4096
#define DM 512
#define HH 8
#define DK 64
#define MT 8192     // B*S

typedef __attribute__((ext_vector_type(8)))  short bf16x8;
typedef __attribute__((ext_vector_type(4)))  float f32x4;
typedef __attribute__((ext_vector_type(16))) float f32x16;
typedef __attribute__((ext_vector_type(4)))  unsigned int u32x4;

#define CQ 0.18033688011112042f   // 0.125 * log2(e), folded into Q projection

__device__ __forceinline__ short f2bs(float x) {
    __hip_bfloat16 h = __float2bfloat16(x);
    return *reinterpret_cast<short*>(&h);
}

__device__ __forceinline__ bf16x8 pack8(const float4& a, const float4& b) {
    bf16x8 r;
    r[0] = f2bs(a.x); r[1] = f2bs(a.y); r[2] = f2bs(a.z); r[3] = f2bs(a.w);
    r[4] = f2bs(b.x); r[5] = f2bs(b.y); r[6] = f2bs(b.z); r[7] = f2bs(b.w);
    return r;
}

__device__ __forceinline__ unsigned cvtpk(float lo, float hi) {
    unsigned r;
    asm("v_cvt_pk_bf16_f32 %0, %1, %2" : "=v"(r) : "v"(lo), "v"(hi));
    return r;
}

__device__ __forceinline__ bf16x8 mk_pb(unsigned a, unsigned b, unsigned c, unsigned d) {
    u32x4 t; t[0] = a; t[1] = b; t[2] = c; t[3] = d;
    return __builtin_bit_cast(bf16x8, t);
}

__device__ __forceinline__ void gld_lds16(const void* gp, void* lp) {
    __builtin_amdgcn_global_load_lds(
        (const __attribute__((address_space(1))) void*)gp,
        (__attribute__((address_space(3))) void*)lp, 16, 0, 0);
}
__device__ __forceinline__ void gld_lds4(const void* gp, void* lp) {
    __builtin_amdgcn_global_load_lds(
        (const __attribute__((address_space(1))) void*)gp,
        (__attribute__((address_space(3))) void*)lp, 4, 0, 0);
}

// ---------------- Fused QKV projection (frag-major K/V outputs) ------------
// Flat grid 1536, XCD-swizzled. Blocks 0..31 also convert mask -> f32 bias.
// Q: bf16 [bh][s][64] scaled by CQ.
// K frag-major: KF[(((bh*128 + s/32)*4 + d/16)*512) + ((s&31)+32*((d>>3)&1))*8 + (d&7)]
// V frag-major: VF[(((bh*256 + s/16)*2 + d/32)*512) + ((d&31)+32*((s>>3)&1))*8 + (s&7)]
// => each 64-key step's K frags (8KB) and V frags (8KB) are CONTIGUOUS.
__global__ __launch_bounds__(256, 4)
void qkv_gemm(const float* __restrict__ Xq, const float* __restrict__ Xk,
              const float* __restrict__ Xv,
              const float* __restrict__ Wq, const float* __restrict__ Wk,
              const float* __restrict__ Wv,
              const float* __restrict__ Bq, const float* __restrict__ Bk,
              const float* __restrict__ Bv,
              const int* __restrict__ mask, float* __restrict__ maskf,
              unsigned short* __restrict__ Yq, unsigned short* __restrict__ Yk,
              unsigned short* __restrict__ Yv)
{
    __shared__ char As[128 * 128];
    __shared__ char Bs[64 * 128];
    const int bid  = blockIdx.x;
    const int t = threadIdx.x;
    if (bid < 32) {
        int i = bid * 256 + t;            // 32*256 = 8192 = B*S
        maskf[i] = mask[i] ? 0.f : -3e38f;
    }
    const int work = (bid & 7) * 192 + (bid >> 3);
    const int gp   = work >> 3;
    const int mat  = gp >> 6;
    const int m0   = (gp & 63) * 128;
    const int n0   = (work & 7) * 64;
    const float* X    = mat == 0 ? Xq : (mat == 1 ? Xk : Xv);
    const float* W    = mat == 0 ? Wq : (mat == 1 ? Wk : Wv);
    const float* bias = mat == 0 ? Bq : (mat == 1 ? Bk : Bv);

    const int l = t & 63, w = t >> 6;
    const int wr = w >> 1, wc = w & 1;
    const int lr = l & 15, lg = l >> 4;
    const int srow = t >> 3, schk = t & 7;
    const int sswz = (schk ^ (srow & 7)) * 16;

    float4 fA[4][2]; float4 fB[2][2];
    auto loadA = [&](int k0) {
        #pragma unroll
        for (int i = 0; i < 4; ++i) {
            const float* p = X + (size_t)(m0 + srow + 32 * i) * DM + k0 + schk * 8;
            fA[i][0] = *(const float4*)p;
            fA[i][1] = *(const float4*)(p + 4);
        }
    };
    auto loadB = [&](int k0) {
        #pragma unroll
        for (int i = 0; i < 2; ++i) {
            const float* p = W + (size_t)(n0 + srow + 32 * i) * DM + k0 + schk * 8;
            fB[i][0] = *(const float4*)p;
            fB[i][1] = *(const float4*)(p + 4);
        }
    };

    loadA(0); loadB(0);

    f32x4 acc[4][2];
    #pragma unroll
    for (int fm = 0; fm < 4; ++fm)
        #pragma unroll
        for (int fn = 0; fn < 2; ++fn) acc[fm][fn] = f32x4{0.f, 0.f, 0.f, 0.f};

    #pragma unroll
    for (int kt = 0; kt < 8; ++kt) {
        bf16x8 wA[4], wB[2];
        #pragma unroll
        for (int i = 0; i < 4; ++i) wA[i] = pack8(fA[i][0], fA[i][1]);
        #pragma unroll
        for (int i = 0; i < 2; ++i) wB[i] = pack8(fB[i][0], fB[i][1]);

        if (kt < 7) { loadA((kt + 1) * 64); loadB((kt + 1) * 64); }

        __syncthreads();
        #pragma unroll
        for (int i = 0; i < 4; ++i)
            *(bf16x8*)(As + (srow + 32 * i) * 128 + sswz) = wA[i];
        #pragma unroll
        for (int i = 0; i < 2; ++i)
            *(bf16x8*)(Bs + (srow + 32 * i) * 128 + sswz) = wB[i];
        __syncthreads();

        #pragma unroll
        for (int kc = 0; kc < 2; ++kc) {
            bf16x8 af[4], bfr[2];
            #pragma unroll
            for (int fm = 0; fm < 4; ++fm) {
                int row = wr * 64 + fm * 16 + lr;
                af[fm] = *(const bf16x8*)(As + row * 128 + (((kc * 4 + lg) ^ (row & 7)) * 16));
            }
            #pragma unroll
            for (int fn = 0; fn < 2; ++fn) {
                int row = wc * 32 + fn * 16 + lr;
                bfr[fn] = *(const bf16x8*)(Bs + row * 128 + (((kc * 4 + lg) ^ (row & 7)) * 16));
            }
            #pragma unroll
            for (int fm = 0; fm < 4; ++fm)
                #pragma unroll
                for (int fn = 0; fn < 2; ++fn)
                    acc[fm][fn] = __builtin_amdgcn_mfma_f32_16x16x32_bf16(af[fm], bfr[fn], acc[fm][fn], 0, 0, 0);
        }
    }

    #pragma unroll
    for (int fm = 0; fm < 4; ++fm) {
        #pragma unroll
        for (int fn = 0; fn < 2; ++fn) {
            int n = n0 + wc * 32 + fn * 16 + lr;
            float bn = bias[n];
            int mbase = m0 + wr * 64 + fm * 16 + lg * 4;
            int h = n >> 6, d = n & 63;
            int bb = mbase >> 12, s0 = mbase & (S - 1);
            if (mat == 0) {
                #pragma unroll
                for (int r = 0; r < 4; ++r)
                    Yq[(((size_t)(bb * HH + h)) * S + s0 + r) * DK + d] =
                        (unsigned short)f2bs((acc[fm][fn][r] + bn) * CQ);
            } else if (mat == 1) {
                int c   = (d >> 4) & 3;
                int hi2 = (d >> 3) & 1;
                int ii  = d & 7;
                size_t blkb = ((((size_t)(bb * HH + h)) * 128 + (s0 >> 5)) * 4 + c) * 512;
                int lanebase = (s0 & 31) + 32 * hi2;
                #pragma unroll
                for (int r = 0; r < 4; ++r)
                    Yk[blkb + (size_t)(lanebase + r) * 8 + ii] =
                        (unsigned short)f2bs(acc[fm][fn][r] + bn);
            } else {
                int dt2  = (d >> 5) & 1;
                int hi_s = (s0 >> 3) & 1;
                int lane = (d & 31) + 32 * hi_s;
                size_t base = ((((size_t)(bb * HH + h)) * 256 + (s0 >> 4)) * 2 + dt2) * 512
                            + (size_t)lane * 8 + (s0 & 7);
                ushort4 u;
                u.x = (unsigned short)f2bs(acc[fm][fn][0] + bn);
                u.y = (unsigned short)f2bs(acc[fm][fn][1] + bn);
                u.z = (unsigned short)f2bs(acc[fm][fn][2] + bn);
                u.w = (unsigned short)f2bs(acc[fm][fn][3] + bn);
                *(ushort4*)(Yv + base) = u;
            }
        }
    }
}

// ---------------- Output projection (XCD-swizzled) -------------------------
__global__ __launch_bounds__(256, 2)
void out_gemm(const short* __restrict__ Xb, const float* __restrict__ W,
              const float* __restrict__ bias, float* __restrict__ Y)
{
    __shared__ char As[128 * 128];
    __shared__ char Bs[64 * 128];
    const int bid  = blockIdx.x;
    const int work = (bid & 7) * 64 + (bid >> 3);
    const int n0 = (work & 7) * 64;
    const int m0 = (work >> 3) * 128;

    const int t = threadIdx.x, l = t & 63, w = t >> 6;
    const int wr = w >> 1, wc = w & 1;
    const int lr = l & 15, lg = l >> 4;
    const int srow = t >> 3, schk = t & 7;
    const int sswz = (schk ^ (srow & 7)) * 16;

    float4 fB[2][2]; bf16x8 rA[4];
    auto loadA = [&](int k0) {
        #pragma unroll
        for (int i = 0; i < 4; ++i)
            rA[i] = *(const bf16x8*)(Xb + (size_t)(m0 + srow + 32 * i) * DM + k0 + schk * 8);
    };
    auto loadB = [&](int k0) {
        #pragma unroll
        for (int i = 0; i < 2; ++i) {
            const float* p = W + (size_t)(n0 + srow + 32 * i) * DM + k0 + schk * 8;
            fB[i][0] = *(const float4*)p;
            fB[i][1] = *(const float4*)(p + 4);
        }
    };

    loadA(0); loadB(0);

    f32x4 acc[4][2];
    #pragma unroll
    for (int fm = 0; fm < 4; ++fm)
        #pragma unroll
        for (int fn = 0; fn < 2; ++fn) acc[fm][fn] = f32x4{0.f, 0.f, 0.f, 0.f};

    #pragma unroll
    for (int kt = 0; kt < 8; ++kt) {
        bf16x8 wA[4], wB[2];
        #pragma unroll
        for (int i = 0; i < 4; ++i) wA[i] = rA[i];
        #pragma unroll
        for (int i = 0; i < 2; ++i) wB[i] = pack8(fB[i][0], fB[i][1]);

        if (kt < 7) { loadA((kt + 1) * 64); loadB((kt + 1) * 64); }

        __syncthreads();
        #pragma unroll
        for (int i = 0; i < 4; ++i)
            *(bf16x8*)(As + (srow + 32 * i) * 128 + sswz) = wA[i];
        #pragma unroll
        for (int i = 0; i < 2; ++i)
            *(bf16x8*)(Bs + (srow + 32 * i) * 128 + sswz) = wB[i];
        __syncthreads();

        #pragma unroll
        for (int kc = 0; kc < 2; ++kc) {
            bf16x8 af[4], bfr[2];
            #pragma unroll
            for (int fm = 0; fm < 4; ++fm) {
                int row = wr * 64 + fm * 16 + lr;
                af[fm] = *(const bf16x8*)(As + row * 128 + (((kc * 4 + lg) ^ (row & 7)) * 16));
            }
            #pragma unroll
            for (int fn = 0; fn < 2; ++fn) {
                int row = wc * 32 + fn * 16 + lr;
                bfr[fn] = *(const bf16x8*)(Bs + row * 128 + (((kc * 4 + lg) ^ (row & 7)) * 16));
            }
            #pragma unroll
            for (int fm = 0; fm < 4; ++fm)
                #pragma unroll
                for (int fn = 0; fn < 2; ++fn)
                    acc[fm][fn] = __builtin_amdgcn_mfma_f32_16x16x32_bf16(af[fm], bfr[fn], acc[fm][fn], 0, 0, 0);
        }
    }

    #pragma unroll
    for (int fm = 0; fm < 4; ++fm) {
        #pragma unroll
        for (int fn = 0; fn < 2; ++fn) {
            int n = n0 + wc * 32 + fn * 16 + lr;
            float bn = bias[n];
            int mbase = m0 + wr * 64 + fm * 16 + lg * 4;
            #pragma unroll
            for (int r = 0; r < 4; ++r)
                Y[(size_t)(mbase + r) * DM + n] = acc[fm][fn][r] + bn;
        }
    }
}

// ---------------- Flash attention: frag-major LDS via global_load_lds ------
// Best-measured structure (126.2 us, conflicts 0). 256 threads / 4 waves
// (qw x kw) / 64 q per block, 1024 blocks. Step's K frags (8KB) + V frags
// (8KB) + mask (256B) staged contiguously via global_load_lds (linear dest,
// zero staging VGPR/VALU); all ds_reads lane-contiguous b128 (conflict-free).
// Double-buffered, 1 barrier/step.
__global__ __launch_bounds__(256, 4)
void flash_mfma(const short* __restrict__ qh,
                const short* __restrict__ kfb,
                const short* __restrict__ vfb,
                const float* __restrict__ maskf,
                unsigned short* __restrict__ att)
{
    const int bid  = blockIdx.x;
    const int work = (bid & 7) * 128 + (bid >> 3);
    const int bh = work >> 6, b = bh >> 3, h = bh & 7;
    const int q0 = (work & 63) * 64;
    const int t = threadIdx.x, w = t >> 6, l = t & 63;
    const int l31 = l & 31, hi = l >> 5;
    const int kw = w & 1, qw = w >> 1;

    __shared__ char sBuf[2 * 16384 + 2 * 256];   // 2x (K 8KB + V 8KB), 2x mask
    char*  B0 = sBuf;
    char*  B1 = sBuf + 16384;
    float* M0 = (float*)(sBuf + 32768);
    float* M1 = (float*)(sBuf + 32768 + 256);

    const short* qg = qh + ((size_t)bh * S + q0 + qw * 32 + l31) * DK;
    bf16x8 qf[4];
    #pragma unroll
    for (int c = 0; c < 4; ++c)
        qf[c] = *(const bf16x8*)(qg + c * 16 + hi * 8);

    f32x16 oc[2];
    #pragma unroll
    for (int dt = 0; dt < 2; ++dt)
        #pragma unroll
        for (int r = 0; r < 16; ++r) oc[dt][r] = 0.f;
    float ls = 0.f;

    // per-step contiguous global bases (bytes): 8KB K + 8KB V each step
    const char* kg0 = (const char*)(kfb + (size_t)bh * 262144) + (size_t)l * 16;
    const char* vg0 = (const char*)(vfb + (size_t)bh * 262144) + (size_t)l * 16;
    const char* mg0 = (const char*)(maskf + b * S) + (size_t)l * 4;

    // wave w stages 4 chunks of 1KB: chunks 0-7 = K, 8-15 = V
    auto stage = [&](char* dst, float* mdst, int step) {
        const char* kg = kg0 + (size_t)step * 8192;
        const char* vg = vg0 + (size_t)step * 8192;
        #pragma unroll
        for (int i = 0; i < 4; ++i) {
            int chunk = w * 4 + i;
            const char* g = (chunk < 8) ? (kg + chunk * 1024) : (vg + (chunk - 8) * 1024);
            gld_lds16(g, dst + chunk * 1024);
        }
        if (w == 0) gld_lds4(mg0 + (size_t)step * 256, mdst);
    };

    auto compute = [&](const char* kv, const float* mlds) {
        // mask-bias C-init (broadcast b128 reads)
        const char* mb = (const char*)mlds + kw * 128 + hi * 16;
        f32x4 m40 = *(const f32x4*)(mb);
        f32x4 m41 = *(const f32x4*)(mb + 32);
        f32x4 m42 = *(const f32x4*)(mb + 64);
        f32x4 m43 = *(const f32x4*)(mb + 96);
        f32x16 sc;
        #pragma unroll
        for (int o = 0; o < 4; ++o) {
            sc[o] = m40[o]; sc[4 + o] = m41[o];
            sc[8 + o] = m42[o]; sc[12 + o] = m43[o];
        }
        // K frags (lane-contiguous b128)
        const char* kbase = kv + kw * 4096 + l * 16;
        bf16x8 kf0 = *(const bf16x8*)(kbase);
        bf16x8 kf1 = *(const bf16x8*)(kbase + 1024);
        bf16x8 kf2 = *(const bf16x8*)(kbase + 2048);
        bf16x8 kf3 = *(const bf16x8*)(kbase + 3072);
        __builtin_amdgcn_s_setprio(1);
        sc = __builtin_amdgcn_mfma_f32_32x32x16_bf16(kf0, qf[0], sc, 0, 0, 0);
        sc = __builtin_amdgcn_mfma_f32_32x32x16_bf16(kf1, qf[1], sc, 0, 0, 0);
        sc = __builtin_amdgcn_mfma_f32_32x32x16_bf16(kf2, qf[2], sc, 0, 0, 0);
        sc = __builtin_amdgcn_mfma_f32_32x32x16_bf16(kf3, qf[3], sc, 0, 0, 0);
        __builtin_amdgcn_s_setprio(0);

        // V frags (this wave's 32 keys)
        const char* vbase = kv + 8192 + kw * 4096 + l * 16;
        bf16x8 vf00 = *(const bf16x8*)(vbase);          // kcl=0 dt=0
        bf16x8 vf01 = *(const bf16x8*)(vbase + 1024);   // kcl=0 dt=1
        bf16x8 vf10 = *(const bf16x8*)(vbase + 2048);   // kcl=1 dt=0
        bf16x8 vf11 = *(const bf16x8*)(vbase + 3072);   // kcl=1 dt=1

        // p = exp2(s); per-lane l partial
        float p[16];
        #pragma unroll
        for (int r = 0; r < 16; ++r) p[r] = exp2f(sc[r]);
        float a0 = 0.f;
        #pragma unroll
        for (int r = 0; r < 16; r += 4)
            a0 += (p[r] + p[r + 1]) + (p[r + 2] + p[r + 3]);
        ls += a0;

        // cvt_pk + permlane32_swap -> PV B-frags
        unsigned A0 = cvtpk(p[0],  p[1]),  B0r = cvtpk(p[2],  p[3]);
        unsigned A1 = cvtpk(p[4],  p[5]),  B1r = cvtpk(p[6],  p[7]);
        unsigned A2 = cvtpk(p[8],  p[9]),  B2r = cvtpk(p[10], p[11]);
        unsigned A3 = cvtpk(p[12], p[13]), B3r = cvtpk(p[14], p[15]);
        asm("v_permlane32_swap_b32 %0, %1" : "+v"(A0), "+v"(A1));
        asm("v_permlane32_swap_b32 %0, %1" : "+v"(B0r), "+v"(B1r));
        asm("v_permlane32_swap_b32 %0, %1" : "+v"(A2), "+v"(A3));
        asm("v_permlane32_swap_b32 %0, %1" : "+v"(B2r), "+v"(B3r));
        bf16x8 pb0 = mk_pb(A0, B0r, A1, B1r);
        bf16x8 pb1 = mk_pb(A2, B2r, A3, B3r);

        // PV
        __builtin_amdgcn_s_setprio(1);
        oc[0] = __builtin_amdgcn_mfma_f32_32x32x16_bf16(vf00, pb0, oc[0], 0, 0, 0);
        oc[1] = __builtin_amdgcn_mfma_f32_32x32x16_bf16(vf01, pb0, oc[1], 0, 0, 0);
        oc[0] = __builtin_amdgcn_mfma_f32_32x32x16_bf16(vf10, pb1, oc[0], 0, 0, 0);
        oc[1] = __builtin_amdgcn_mfma_f32_32x32x16_bf16(vf11, pb1, oc[1], 0, 0, 0);
        __builtin_amdgcn_s_setprio(0);
    };

    stage(B0, M0, 0);
    __syncthreads();                     // drains vmcnt -> buf0 ready

    const int NT = S / 64;               // 64 (even)
    for (int it = 0; it < NT / 2; ++it) {
        const int s0 = it * 2;
        stage(B1, M1, s0 + 1);           // always valid (s0+1 <= 63)
        compute(B0, M0);
        __syncthreads();
        if (s0 + 2 < NT) stage(B0, M0, s0 + 2);
        compute(B1, M1);
        __syncthreads();
    }

    // ---- cross-wave (kw) reduction, then normalize + write (reuse sBuf)
    float* scr = (float*)sBuf;
    float* pp  = scr + (size_t)(qw * 64 + l) * 33;
    if (kw == 1) {
        #pragma unroll
        for (int r = 0; r < 16; ++r) { pp[r] = oc[0][r]; pp[16 + r] = oc[1][r]; }
        pp[32] = ls;
    }
    __syncthreads();
    if (kw == 0) {
        #pragma unroll
        for (int r = 0; r < 16; ++r) { oc[0][r] += pp[r]; oc[1][r] += pp[16 + r]; }
        ls += pp[32];
        ls += __shfl_xor(ls, 32);
        const float linv = 1.0f / ls;
        unsigned short* ap = att + ((size_t)(b * S + q0 + qw * 32 + l31)) * DM + h * DK;
        #pragma unroll
        for (int dt = 0; dt < 2; ++dt)
            #pragma unroll
            for (int g = 0; g < 4; ++g) {
                uint2 u;
                u.x = cvtpk(oc[dt][g * 4 + 0] * linv, oc[dt][g * 4 + 1] * linv);
                u.y = cvtpk(oc[dt][g * 4 + 2] * linv, oc[dt][g * 4 + 3] * linv);
                *(uint2*)(ap + dt * 32 + g * 8 + hi * 4) = u;
            }
    }
}

extern "C" void kernel_launch(void* const* d_in, const int* in_sizes, int n_in,
                              void* d_out, int out_size, void* d_ws, size_t ws_size,
                              hipStream_t stream) {
    const float* q    = (const float*)d_in[0];
    const float* k    = (const float*)d_in[1];
    const float* v    = (const float*)d_in[2];
    const int*   mask = (const int*)  d_in[3];
    const float* wq   = (const float*)d_in[4];
    const float* bq   = (const float*)d_in[5];
    const float* wk   = (const float*)d_in[6];
    const float* bk   = (const float*)d_in[7];
    const float* wv   = (const float*)d_in[8];
    const float* bv   = (const float*)d_in[9];
    const float* wo   = (const float*)d_in[10];
    const float* bo   = (const float*)d_in[11];
    float* out = (float*)d_out;

    char* wsb = (char*)d_ws;
    unsigned short* qh    = (unsigned short*)(wsb);
    unsigned short* kfb   = (unsigned short*)(wsb + (size_t)8  * 1024 * 1024);
    unsigned short* vfb   = (unsigned short*)(wsb + (size_t)16 * 1024 * 1024);
    unsigned short* att   = (unsigned short*)(wsb + (size_t)24 * 1024 * 1024);
    float*          maskf = (float*)         (wsb + (size_t)32 * 1024 * 1024);

    dim3 blk(256);
    qkv_gemm<<<dim3(1536), blk, 0, stream>>>(q, k, v, wq, wk, wv, bq, bk, bv,
                                     mask, maskf, qh, kfb, vfb);

    flash_mfma<<<dim3(1024), blk, 0, stream>>>((const short*)qh, (const short*)kfb,
                                     (const short*)vfb, maskf, att);

    out_gemm<<<dim3(512), blk, 0, stream>>>((const short*)att, wo, bo, out);
}